// Round 14
// baseline (279.576 us; speedup 1.0000x reference)
//
#include <hip/hip_runtime.h>
#include <stdint.h>

// Problem constants
constexpr int NB = 8, NH = 8, NN = 1024, DK = 64, ED = 16;
constexpr long QSZ = (long)NB * NH * NN * DK;       // 4,194,304

typedef _Float16 h8 __attribute__((ext_vector_type(8)));
typedef _Float16 h4 __attribute__((ext_vector_type(4)));
typedef _Float16 h2 __attribute__((ext_vector_type(2)));
typedef float f4 __attribute__((ext_vector_type(4)));
typedef float fv16 __attribute__((ext_vector_type(16)));

// ws layout (bytes)
constexpr size_t OFF_QH = 0;                         // 8 MiB fp16 (pre-scaled by 0.125*log2e)
constexpr size_t OFF_KH = 8388608;                   // 8 MiB fp16
constexpr size_t OFF_VT = 16777216;                  // 8 MiB fp16 (transposed [bh][d][k])
constexpr size_t OFF_BIAS = 25165824;                // 16 MiB fp16 (bias*log2e, masked=-30000)
constexpr size_t WS_NEED = OFF_BIAS + 16777216;

constexpr float LG2E = 1.4426950408889634f;          // log2(e)
constexpr float C2 = 2.8853900817779268f;            // 2*log2(e)
constexpr float QS = 0.125f * LG2E;                  // fold 1/sqrt(dk) and log2e into Q

static __device__ __forceinline__ float fexp2(float x) {
  float r; asm("v_exp_f32 %0, %1" : "=v"(r) : "v"(x)); return r;
}
static __device__ __forceinline__ float frcp(float x) {
  float r; asm("v_rcp_f32 %0, %1" : "=v"(r) : "v"(x)); return r;
}
static __device__ __forceinline__ h2 pkrtz(float a, float b) {
  return __builtin_bit_cast(h2, __builtin_amdgcn_cvt_pkrtz(a, b));
}
// async global->LDS, 16B per lane; lptr must be WAVE-UNIFORM (HW scatters lane i to lptr + i*16)
static __device__ __forceinline__ void gl16(const void* g, void* l) {
  __builtin_amdgcn_global_load_lds(
      (const __attribute__((address_space(1))) uint32_t*)g,
      (__attribute__((address_space(3))) uint32_t*)l, 16, 0, 0);
}

// ---------- merged front kernel: bias MLP (blocks 0..8191) + Q/K/V prep (8192..17407) ----------
// Bias blocks self-detect mask width (scan first 4KB: int32 0/1 never has nonzero
// bytes at %4!=0) -> no separate detect dispatch, no flag dependency.
// tanh chain uses PAIRED reciprocals: rq = rcp(d0*d1); r0 = rq*d1; r1 = rq*d0
// (trans insts per pair 4 -> 3; clamp exp arg at 30 so d0*d1 <= 2^60, no overflow/NaN).
__global__ __launch_bounds__(256, 3) void k_front(
    const float* __restrict__ Q, const float* __restrict__ K, const float* __restrict__ V,
    const void* __restrict__ maskp, const float* __restrict__ edge,
    const float* __restrict__ W1, const float* __restrict__ b1,
    const float* __restrict__ W2, const float* __restrict__ b2,
    _Float16* __restrict__ Qh, _Float16* __restrict__ Kh, _Float16* __restrict__ Vt,
    _Float16* __restrict__ biasM) {
  int bid = blockIdx.x;
  int tid = threadIdx.x;
  if (bid >= 8192) {
    // ---------------- prep path ----------------
    int pb_ = bid - 8192;
    if (pb_ < 8192) {
      int i = pb_ * 256 + tid;
      const int n4 = (int)(QSZ / 4);
      if (i < n4) {
        float4 v = reinterpret_cast<const float4*>(Q)[i];
        h4 o; o[0] = (_Float16)(v.x * QS); o[1] = (_Float16)(v.y * QS);
              o[2] = (_Float16)(v.z * QS); o[3] = (_Float16)(v.w * QS);
        reinterpret_cast<h4*>(Qh)[i] = o;
      } else {
        int j = i - n4;
        float4 v = reinterpret_cast<const float4*>(K)[j];
        h4 o; o[0] = (_Float16)v.x; o[1] = (_Float16)v.y;
              o[2] = (_Float16)v.z; o[3] = (_Float16)v.w;
        reinterpret_cast<h4*>(Kh)[j] = o;
      }
    } else {
      int wid = ((pb_ - 8192) * 256 + tid) >> 6;
      int lane = tid & 63;
      int bh = wid >> 6;
      int k0 = (wid & 63) << 4;
      const float* Vb = V + (long)bh * NN * DK;
      _Float16* Vo = Vt + (long)bh * DK * NN + (long)lane * NN + k0;
      h8 p0, p1;
#pragma unroll
      for (int i = 0; i < 16; ++i) {
        float v = Vb[(long)(k0 + i) * DK + lane];
        if (i < 8) p0[i] = (_Float16)v; else p1[i - 8] = (_Float16)v;
      }
      *reinterpret_cast<h8*>(Vo) = p0;
      *reinterpret_cast<h8*>(Vo + 8) = p1;
    }
    return;
  }
  // ---------------- bias path ----------------
  int bq = bid;
  int w = tid >> 6, l = tid & 63;
  int h = l >> 5, c31 = l & 31;

  // self-detect mask element width: scan first 4096 bytes (coalesced, L2-hot)
  __shared__ int sh4[4];
  {
    int4 mv = reinterpret_cast<const int4*>(maskp)[tid];
    int any = (mv.x | mv.y | mv.z | mv.w) & 0xFFFFFF00;
    unsigned long long bal = __ballot(any != 0);
    if ((tid & 63) == 0) sh4[tid >> 6] = (bal != 0) ? 1 : 0;
  }
  __syncthreads();
  bool isbool = (sh4[0] | sh4[1] | sh4[2] | sh4[3]) != 0;

  h8 aw0, aw1;
#pragma unroll
  for (int j = 0; j < 8; ++j) {
    aw0[j] = (_Float16)(W1[(8 * h + j) * 64 + 0  + c31] * C2);
    aw1[j] = (_Float16)(W1[(8 * h + j) * 64 + 32 + c31] * C2);
  }
  h2 pb[16], pw[16];
  float sw = 0.f;
#pragma unroll
  for (int r = 0; r < 16; ++r) {
    int dr = (r & 3) + 8 * (r >> 2) + 4 * h;
    float b0 = b1[dr] * C2, b1v = b1[32 + dr] * C2;
    float w0 = W2[dr], w1v = W2[32 + dr];
    pb[r] = pkrtz(b0, b1v);
    pw[r] = pkrtz(w0, w1v);
    sw += w0 + w1v;
  }
  sw += __shfl_xor(sw, 32, 64);
  float base = (sw + b2[0]) * LG2E;

  const char* erow_b = (const char*)(edge + (long)bq * NN * ED);  // 64B per kv row
  _Float16* orow = biasM + (long)bq * NN;
  const int* mrowi = (const int*)maskp + (long)bq * NN;
  const unsigned char* mrowb = (const unsigned char*)maskp + (long)bq * NN;

  fv16 z;
#pragma unroll
  for (int r = 0; r < 16; ++r) z[r] = 0.f;

  int kq0 = w * 256;
  int m4[4];
#pragma unroll
  for (int p = 0; p < 4; ++p) {
    int idx = kq0 + p * 64 + 32 * h + c31;
    m4[p] = isbool ? (int)mrowb[idx] : mrowi[idx];
  }

  __shared__ __align__(16) float ebuf[4][2][1024];
  int r4 = l >> 2;
  int csw = ((l & 3) * 16) ^ ((r4 & 3) << 4);
#define STAGE(buf, p) do { \
    const char* src_ = erow_b + (long)(kq0 + (p) * 64) * 64; \
    char* dst_ = (char*)&ebuf[w][buf][0]; \
    gl16(src_ + (long)(r4) * 64 + csw, dst_); \
    gl16(src_ + (long)(16 + r4) * 64 + csw, dst_ + 1024); \
    gl16(src_ + (long)(32 + r4) * 64 + csw, dst_ + 2048); \
    gl16(src_ + (long)(48 + r4) * 64 + csw, dst_ + 3072); \
  } while (0)

  int sw0 = (c31 & 3) << 4;
  float res[4];
  STAGE(0, 0);
#pragma unroll
  for (int p = 0; p < 4; ++p) {
    if (p < 3) STAGE((p + 1) & 1, p + 1);
    if (p < 3) { asm volatile("s_waitcnt vmcnt(4)" ::: "memory"); }
    else       { asm volatile("s_waitcnt vmcnt(0)" ::: "memory"); }
    const char* tb = (const char*)&ebuf[w][p & 1][0];
    f4 e0a = *(const f4*)(tb + c31 * 64 + ((h * 32) ^ sw0));
    f4 e0b = *(const f4*)(tb + c31 * 64 + ((h * 32 + 16) ^ sw0));
    f4 e1a = *(const f4*)(tb + (32 + c31) * 64 + ((h * 32) ^ sw0));
    f4 e1b = *(const f4*)(tb + (32 + c31) * 64 + ((h * 32 + 16) ^ sw0));
    union { h8 v; h2 q[4]; } u0, u1;
    u0.q[0] = pkrtz(e0a[0], e0a[1]); u0.q[1] = pkrtz(e0a[2], e0a[3]);
    u0.q[2] = pkrtz(e0b[0], e0b[1]); u0.q[3] = pkrtz(e0b[2], e0b[3]);
    u1.q[0] = pkrtz(e1a[0], e1a[1]); u1.q[1] = pkrtz(e1a[2], e1a[3]);
    u1.q[2] = pkrtz(e1b[0], e1b[1]); u1.q[3] = pkrtz(e1b[2], e1b[3]);
    fv16 hA0 = __builtin_amdgcn_mfma_f32_32x32x16_f16(aw0, u0.v, z, 0, 0, 0);
    fv16 hA1 = __builtin_amdgcn_mfma_f32_32x32x16_f16(aw0, u1.v, z, 0, 0, 0);
    fv16 hB0 = __builtin_amdgcn_mfma_f32_32x32x16_f16(aw1, u0.v, z, 0, 0, 0);
    fv16 hB1 = __builtin_amdgcn_mfma_f32_32x32x16_f16(aw1, u1.v, z, 0, 0, 0);
    float a00 = 0.f, a01 = 0.f, a10 = 0.f, a11 = 0.f;
#pragma unroll
    for (int r = 0; r < 16; r += 2) {
      float b0A = (float)pb[r][0], b1A = (float)pb[r + 1][0];
      float w0A = (float)pw[r][0], w1A = (float)pw[r + 1][0];
      float b0B = (float)pb[r][1], b1B = (float)pb[r + 1][1];
      float w0B = (float)pw[r][1], w1B = (float)pw[r + 1][1];
      {
        float d0 = fexp2(fminf(hA0[r] + b0A, 30.f)) + 1.f;
        float d1 = fexp2(fminf(hA0[r + 1] + b1A, 30.f)) + 1.f;
        float rq = frcp(d0 * d1);
        a00 = fmaf(w0A, rq * d1, a00);
        a01 = fmaf(w1A, rq * d0, a01);
      }
      {
        float d0 = fexp2(fminf(hB0[r] + b0B, 30.f)) + 1.f;
        float d1 = fexp2(fminf(hB0[r + 1] + b1B, 30.f)) + 1.f;
        float rq = frcp(d0 * d1);
        a00 = fmaf(w0B, rq * d1, a00);
        a01 = fmaf(w1B, rq * d0, a01);
      }
      {
        float d0 = fexp2(fminf(hA1[r] + b0A, 30.f)) + 1.f;
        float d1 = fexp2(fminf(hA1[r + 1] + b1A, 30.f)) + 1.f;
        float rq = frcp(d0 * d1);
        a10 = fmaf(w0A, rq * d1, a10);
        a11 = fmaf(w1A, rq * d0, a11);
      }
      {
        float d0 = fexp2(fminf(hB1[r] + b0B, 30.f)) + 1.f;
        float d1 = fexp2(fminf(hB1[r + 1] + b1B, 30.f)) + 1.f;
        float rq = frcp(d0 * d1);
        a10 = fmaf(w0B, rq * d1, a10);
        a11 = fmaf(w1B, rq * d0, a11);
      }
    }
    float p0 = a00 + a01;
    float p1 = a10 + a11;
    p0 += __shfl_xor(p0, 32, 64);
    p1 += __shfl_xor(p1, 32, 64);
    res[p] = h ? p1 : p0;
  }
#undef STAGE
#pragma unroll
  for (int p = 0; p < 4; ++p) {
    int idx = kq0 + p * 64 + 32 * h + c31;
    orow[idx] = m4[p] ? (_Float16)(-30000.0f) : (_Float16)fmaf(-C2, res[p], base);
  }
}

// ---------- fused attention (unchanged from R11-R13 winner) ----------
__global__ __launch_bounds__(256) void k_attn(
    const _Float16* __restrict__ Qh, const _Float16* __restrict__ Kh,
    const _Float16* __restrict__ Vt, const _Float16* __restrict__ biasH,
    float* __restrict__ ctx, float* __restrict__ attn) {
  int bid = blockIdx.x;
  int b = bid & 7;           // XCD-pinned batch
  int t_ = bid >> 3;
  int hh = t_ & 7;
  int qb = t_ >> 3;
  int bh = b * 8 + hh;
  int tid = threadIdx.x;
  int w = tid >> 6, l = tid & 63;
  int g = l >> 4, s = l & 15;
  int q0 = qb * 64 + w * 16;

  const _Float16* Qw = Qh + ((long)bh * NN + q0) * DK;
  const char* Kbase = (const char*)(Kh + (long)bh * NN * DK);
  const char* Vbase = (const char*)(Vt + (long)bh * DK * NN);
  const char* Bbase = (const char*)(biasH + (long)b * NN * NN + (long)(qb * 64) * NN);
  h8 aQ0 = *reinterpret_cast<const h8*>(Qw + s * DK + 8 * g);
  h8 aQ1 = *reinterpret_cast<const h8*>(Qw + s * DK + 32 + 8 * g);
  const f4 z4 = {0.f, 0.f, 0.f, 0.f};

  __shared__ __align__(16) _Float16 kt[2][32 * 64];
  __shared__ __align__(16) _Float16 vt2[2][64 * 32];
  __shared__ __align__(16) _Float16 bt[2][64 * 32];
  __shared__ float pf[4][16][33];

  int krow = tid >> 3;
  int kcol = ((tid & 7) * 16) ^ ((krow & 7) << 4);
  int vrow = tid >> 2;
  int vcol = ((tid & 3) * 16) ^ ((vrow & 3) << 4);
  int brow = tid >> 2;
  int bcol = (tid & 3) * 16;
  int wofs = w << 10;

  int ksw = (s & 7) << 4;
  int vswz = (s & 3) << 4;

#define STK(buf, c0) gl16(Kbase + (long)((c0) + krow) * 128 + kcol, (char*)kt[buf] + wofs)
#define STV(buf, c0) gl16(Vbase + (long)vrow * 2048 + (c0) * 2 + vcol, (char*)vt2[buf] + wofs)
#define STB(buf, c0) gl16(Bbase + (long)brow * 2048 + (c0) * 2 + bcol, (char*)bt[buf] + wofs)
#define BIAS(buf, j, kvl) ((float)*(const _Float16*)((const char*)bt[buf] + (w * 16 + 4 * g + (j)) * 64 + (kvl) * 2))

  float ls0 = 0.f, ls1 = 0.f, ls2 = 0.f, ls3 = 0.f;
  STK(0, 0); STB(0, 0);
  {
    int buf = 0;
    for (int c0 = 0; c0 < NN; c0 += 32, buf ^= 1) {
      __syncthreads();
      if (c0 + 32 < NN) { STK(buf ^ 1, c0 + 32); STB(buf ^ 1, c0 + 32); }
      const char* kbuf = (const char*)kt[buf];
      h8 k0 = *(const h8*)(kbuf + s * 128 + ((16 * g) ^ ksw));
      h8 k1 = *(const h8*)(kbuf + s * 128 + ((64 + 16 * g) ^ ksw));
      f4 acc = __builtin_amdgcn_mfma_f32_16x16x32_f16(aQ0, k0, z4, 0, 0, 0);
      acc = __builtin_amdgcn_mfma_f32_16x16x32_f16(aQ1, k1, acc, 0, 0, 0);
      ls0 += fexp2(acc[0] + BIAS(buf, 0, s));
      ls1 += fexp2(acc[1] + BIAS(buf, 1, s));
      ls2 += fexp2(acc[2] + BIAS(buf, 2, s));
      ls3 += fexp2(acc[3] + BIAS(buf, 3, s));
      k0 = *(const h8*)(kbuf + (16 + s) * 128 + ((16 * g) ^ ksw));
      k1 = *(const h8*)(kbuf + (16 + s) * 128 + ((64 + 16 * g) ^ ksw));
      acc = __builtin_amdgcn_mfma_f32_16x16x32_f16(aQ0, k0, z4, 0, 0, 0);
      acc = __builtin_amdgcn_mfma_f32_16x16x32_f16(aQ1, k1, acc, 0, 0, 0);
      ls0 += fexp2(acc[0] + BIAS(buf, 0, 16 + s));
      ls1 += fexp2(acc[1] + BIAS(buf, 1, 16 + s));
      ls2 += fexp2(acc[2] + BIAS(buf, 2, 16 + s));
      ls3 += fexp2(acc[3] + BIAS(buf, 3, 16 + s));
    }
  }
#pragma unroll
  for (int m = 1; m < 16; m <<= 1) {
    ls0 += __shfl_xor(ls0, m, 64);
    ls1 += __shfl_xor(ls1, m, 64);
    ls2 += __shfl_xor(ls2, m, 64);
    ls3 += __shfl_xor(ls3, m, 64);
  }
  float iv0 = frcp(ls0), iv1 = frcp(ls1), iv2 = frcp(ls2), iv3 = frcp(ls3);

  f4 ca0 = {0.f,0.f,0.f,0.f}, ca1 = {0.f,0.f,0.f,0.f};
  f4 ca2 = {0.f,0.f,0.f,0.f}, ca3 = {0.f,0.f,0.f,0.f};
  float* attnw = attn + ((long)bh * NN + q0) * NN;
  int sr = l >> 3, sc = (l & 7) * 4;
  __syncthreads();
  STK(0, 0); STV(0, 0); STB(0, 0);
  {
    int buf = 0;
    for (int c0 = 0; c0 < NN; c0 += 32, buf ^= 1) {
      __syncthreads();
      if (c0 + 32 < NN) { STK(buf ^ 1, c0 + 32); STV(buf ^ 1, c0 + 32); STB(buf ^ 1, c0 + 32); }
      const char* kbuf = (const char*)kt[buf];
      const char* vbuf = (const char*)vt2[buf];
      h8 k0 = *(const h8*)(kbuf + s * 128 + ((16 * g) ^ ksw));
      h8 k1 = *(const h8*)(kbuf + s * 128 + ((64 + 16 * g) ^ ksw));
      f4 acc = __builtin_amdgcn_mfma_f32_16x16x32_f16(aQ0, k0, z4, 0, 0, 0);
      acc = __builtin_amdgcn_mfma_f32_16x16x32_f16(aQ1, k1, acc, 0, 0, 0);
      pf[w][4 * g + 0][s] = fexp2(acc[0] + BIAS(buf, 0, s)) * iv0;
      pf[w][4 * g + 1][s] = fexp2(acc[1] + BIAS(buf, 1, s)) * iv1;
      pf[w][4 * g + 2][s] = fexp2(acc[2] + BIAS(buf, 2, s)) * iv2;
      pf[w][4 * g + 3][s] = fexp2(acc[3] + BIAS(buf, 3, s)) * iv3;
      k0 = *(const h8*)(kbuf + (16 + s) * 128 + ((16 * g) ^ ksw));
      k1 = *(const h8*)(kbuf + (16 + s) * 128 + ((64 + 16 * g) ^ ksw));
      acc = __builtin_amdgcn_mfma_f32_16x16x32_f16(aQ0, k0, z4, 0, 0, 0);
      acc = __builtin_amdgcn_mfma_f32_16x16x32_f16(aQ1, k1, acc, 0, 0, 0);
      pf[w][4 * g + 0][16 + s] = fexp2(acc[0] + BIAS(buf, 0, 16 + s)) * iv0;
      pf[w][4 * g + 1][16 + s] = fexp2(acc[1] + BIAS(buf, 1, 16 + s)) * iv1;
      pf[w][4 * g + 2][16 + s] = fexp2(acc[2] + BIAS(buf, 2, 16 + s)) * iv2;
      pf[w][4 * g + 3][16 + s] = fexp2(acc[3] + BIAS(buf, 3, 16 + s)) * iv3;
      f4 row0 = *reinterpret_cast<const f4*>(&pf[w][sr][sc]);
      f4 row1 = *reinterpret_cast<const f4*>(&pf[w][sr + 8][sc]);
      *reinterpret_cast<f4*>(attnw + (long)sr * NN + c0 + sc) = row0;
      *reinterpret_cast<f4*>(attnw + (long)(sr + 8) * NN + c0 + sc) = row1;
      f4 pa = *reinterpret_cast<const f4*>(&pf[w][s][8 * g]);
      f4 pb4 = *reinterpret_cast<const f4*>(&pf[w][s][8 * g + 4]);
      union { h8 v; h2 q[4]; } up;
      up.q[0] = pkrtz(pa[0], pa[1]);  up.q[1] = pkrtz(pa[2], pa[3]);
      up.q[2] = pkrtz(pb4[0], pb4[1]); up.q[3] = pkrtz(pb4[2], pb4[3]);
      h8 aP = up.v;
      h8 bv0 = *(const h8*)(vbuf + (s)      * 64 + ((16 * g) ^ vswz));
      h8 bv1 = *(const h8*)(vbuf + (16 + s) * 64 + ((16 * g) ^ vswz));
      h8 bv2 = *(const h8*)(vbuf + (32 + s) * 64 + ((16 * g) ^ vswz));
      h8 bv3 = *(const h8*)(vbuf + (48 + s) * 64 + ((16 * g) ^ vswz));
      ca0 = __builtin_amdgcn_mfma_f32_16x16x32_f16(aP, bv0, ca0, 0, 0, 0);
      ca1 = __builtin_amdgcn_mfma_f32_16x16x32_f16(aP, bv1, ca1, 0, 0, 0);
      ca2 = __builtin_amdgcn_mfma_f32_16x16x32_f16(aP, bv2, ca2, 0, 0, 0);
      ca3 = __builtin_amdgcn_mfma_f32_16x16x32_f16(aP, bv3, ca3, 0, 0, 0);
    }
  }
  float* cw = ctx + ((long)bh * NN + q0) * DK;
#pragma unroll
  for (int j = 0; j < 4; ++j) {
    cw[(4 * g + j) * DK + 0  + s] = ca0[j];
    cw[(4 * g + j) * DK + 16 + s] = ca1[j];
    cw[(4 * g + j) * DK + 32 + s] = ca2[j];
    cw[(4 * g + j) * DK + 48 + s] = ca3[j];
  }
#undef STK
#undef STV
#undef STB
#undef BIAS
}

extern "C" void kernel_launch(void* const* d_in, const int* in_sizes, int n_in,
                              void* d_out, int out_size, void* d_ws, size_t ws_size,
                              hipStream_t stream) {
  const float* Q = (const float*)d_in[0];
  const float* K = (const float*)d_in[1];
  const float* V = (const float*)d_in[2];
  const void* mask = d_in[3];
  const float* edge = (const float*)d_in[4];
  const float* W1 = (const float*)d_in[5];
  const float* b1 = (const float*)d_in[6];
  const float* W2 = (const float*)d_in[7];
  const float* b2 = (const float*)d_in[8];
  float* ctx = (float*)d_out;
  float* attn = ctx + QSZ;                  // outputs: context then attn
  char* ws = (char*)d_ws;
  if (ws_size < WS_NEED) return;
  _Float16* Qh = (_Float16*)(ws + OFF_QH);
  _Float16* Kh = (_Float16*)(ws + OFF_KH);
  _Float16* Vt = (_Float16*)(ws + OFF_VT);
  _Float16* biasM = (_Float16*)(ws + OFF_BIAS);

  k_front<<<17408, 256, 0, stream>>>(Q, K, V, mask, edge, W1, b1, W2, b2,
                                     Qh, Kh, Vt, biasM);
  k_attn<<<1024, 256, 0, stream>>>(Qh, Kh, Vt, biasM, ctx, attn);
}

// Round 15
// 269.046 us; speedup vs baseline: 1.0391x; 1.0391x over previous
//
#include <hip/hip_runtime.h>
#include <stdint.h>

// Problem constants
constexpr int NB = 8, NH = 8, NN = 1024, DK = 64, ED = 16;
constexpr long QSZ = (long)NB * NH * NN * DK;       // 4,194,304

typedef _Float16 h8 __attribute__((ext_vector_type(8)));
typedef _Float16 h4 __attribute__((ext_vector_type(4)));
typedef _Float16 h2 __attribute__((ext_vector_type(2)));
typedef float f4 __attribute__((ext_vector_type(4)));
typedef float fv16 __attribute__((ext_vector_type(16)));

// ws layout (bytes)
constexpr size_t OFF_QH = 0;                         // 8 MiB fp16 (pre-scaled by 0.125*log2e)
constexpr size_t OFF_KH = 8388608;                   // 8 MiB fp16
constexpr size_t OFF_VT = 16777216;                  // 8 MiB fp16 (transposed [bh][d][k])
constexpr size_t OFF_BIAS = 25165824;                // 16 MiB fp16 (bias*log2e, masked=-30000)
constexpr size_t WS_NEED = OFF_BIAS + 16777216;

constexpr float LG2E = 1.4426950408889634f;          // log2(e)
constexpr float C2 = 2.8853900817779268f;            // 2*log2(e)
constexpr float QS = 0.125f * LG2E;                  // fold 1/sqrt(dk) and log2e into Q

static __device__ __forceinline__ float fexp2(float x) {
  float r; asm("v_exp_f32 %0, %1" : "=v"(r) : "v"(x)); return r;
}
static __device__ __forceinline__ float frcp(float x) {
  float r; asm("v_rcp_f32 %0, %1" : "=v"(r) : "v"(x)); return r;
}
static __device__ __forceinline__ h2 pkrtz(float a, float b) {
  return __builtin_bit_cast(h2, __builtin_amdgcn_cvt_pkrtz(a, b));
}
// async global->LDS, 16B per lane; lptr must be WAVE-UNIFORM (HW scatters lane i to lptr + i*16)
static __device__ __forceinline__ void gl16(const void* g, void* l) {
  __builtin_amdgcn_global_load_lds(
      (const __attribute__((address_space(1))) uint32_t*)g,
      (__attribute__((address_space(3))) uint32_t*)l, 16, 0, 0);
}

// ---------- merged front kernel: bias MLP (blocks 0..8191) + Q/K/V prep (8192..17407) ----------
// Bias blocks self-detect mask width (scan first 4KB: int32 0/1 never has nonzero
// bytes at %4!=0) -> no separate detect dispatch, no flag dependency.
// __launch_bounds__(256,4): cap VGPR at 128 to guarantee 4 waves/SIMD so the
// edge-BW phase and trans/VALU burst overlap across waves (R13 was (256,3)).
__global__ __launch_bounds__(256, 4) void k_front(
    const float* __restrict__ Q, const float* __restrict__ K, const float* __restrict__ V,
    const void* __restrict__ maskp, const float* __restrict__ edge,
    const float* __restrict__ W1, const float* __restrict__ b1,
    const float* __restrict__ W2, const float* __restrict__ b2,
    _Float16* __restrict__ Qh, _Float16* __restrict__ Kh, _Float16* __restrict__ Vt,
    _Float16* __restrict__ biasM) {
  int bid = blockIdx.x;
  int tid = threadIdx.x;
  if (bid >= 8192) {
    // ---------------- prep path ----------------
    int pb_ = bid - 8192;
    if (pb_ < 8192) {
      int i = pb_ * 256 + tid;
      const int n4 = (int)(QSZ / 4);
      if (i < n4) {
        float4 v = reinterpret_cast<const float4*>(Q)[i];
        h4 o; o[0] = (_Float16)(v.x * QS); o[1] = (_Float16)(v.y * QS);
              o[2] = (_Float16)(v.z * QS); o[3] = (_Float16)(v.w * QS);
        reinterpret_cast<h4*>(Qh)[i] = o;
      } else {
        int j = i - n4;
        float4 v = reinterpret_cast<const float4*>(K)[j];
        h4 o; o[0] = (_Float16)v.x; o[1] = (_Float16)v.y;
              o[2] = (_Float16)v.z; o[3] = (_Float16)v.w;
        reinterpret_cast<h4*>(Kh)[j] = o;
      }
    } else {
      int wid = ((pb_ - 8192) * 256 + tid) >> 6;
      int lane = tid & 63;
      int bh = wid >> 6;
      int k0 = (wid & 63) << 4;
      const float* Vb = V + (long)bh * NN * DK;
      _Float16* Vo = Vt + (long)bh * DK * NN + (long)lane * NN + k0;
      h8 p0, p1;
#pragma unroll
      for (int i = 0; i < 16; ++i) {
        float v = Vb[(long)(k0 + i) * DK + lane];
        if (i < 8) p0[i] = (_Float16)v; else p1[i - 8] = (_Float16)v;
      }
      *reinterpret_cast<h8*>(Vo) = p0;
      *reinterpret_cast<h8*>(Vo + 8) = p1;
    }
    return;
  }
  // ---------------- bias path ----------------
  int bq = bid;
  int w = tid >> 6, l = tid & 63;
  int h = l >> 5, c31 = l & 31;

  // self-detect mask element width: scan first 4096 bytes (coalesced, L2-hot)
  __shared__ int sh4[4];
  {
    int4 mv = reinterpret_cast<const int4*>(maskp)[tid];
    int any = (mv.x | mv.y | mv.z | mv.w) & 0xFFFFFF00;
    unsigned long long bal = __ballot(any != 0);
    if ((tid & 63) == 0) sh4[tid >> 6] = (bal != 0) ? 1 : 0;
  }
  __syncthreads();
  bool isbool = (sh4[0] | sh4[1] | sh4[2] | sh4[3]) != 0;

  h8 aw0, aw1;
#pragma unroll
  for (int j = 0; j < 8; ++j) {
    aw0[j] = (_Float16)(W1[(8 * h + j) * 64 + 0  + c31] * C2);
    aw1[j] = (_Float16)(W1[(8 * h + j) * 64 + 32 + c31] * C2);
  }
  h2 pb[16], pw[16];
  float sw = 0.f;
#pragma unroll
  for (int r = 0; r < 16; ++r) {
    int dr = (r & 3) + 8 * (r >> 2) + 4 * h;
    float b0 = b1[dr] * C2, b1v = b1[32 + dr] * C2;
    float w0 = W2[dr], w1v = W2[32 + dr];
    pb[r] = pkrtz(b0, b1v);
    pw[r] = pkrtz(w0, w1v);
    sw += w0 + w1v;
  }
  sw += __shfl_xor(sw, 32, 64);
  float base = (sw + b2[0]) * LG2E;

  const char* erow_b = (const char*)(edge + (long)bq * NN * ED);  // 64B per kv row
  _Float16* orow = biasM + (long)bq * NN;
  const int* mrowi = (const int*)maskp + (long)bq * NN;
  const unsigned char* mrowb = (const unsigned char*)maskp + (long)bq * NN;

  fv16 z;
#pragma unroll
  for (int r = 0; r < 16; ++r) z[r] = 0.f;

  int kq0 = w * 256;
  int m4[4];
#pragma unroll
  for (int p = 0; p < 4; ++p) {
    int idx = kq0 + p * 64 + 32 * h + c31;
    m4[p] = isbool ? (int)mrowb[idx] : mrowi[idx];
  }

  __shared__ __align__(16) float ebuf[4][2][1024];
  int r4 = l >> 2;
  int csw = ((l & 3) * 16) ^ ((r4 & 3) << 4);
#define STAGE(buf, p) do { \
    const char* src_ = erow_b + (long)(kq0 + (p) * 64) * 64; \
    char* dst_ = (char*)&ebuf[w][buf][0]; \
    gl16(src_ + (long)(r4) * 64 + csw, dst_); \
    gl16(src_ + (long)(16 + r4) * 64 + csw, dst_ + 1024); \
    gl16(src_ + (long)(32 + r4) * 64 + csw, dst_ + 2048); \
    gl16(src_ + (long)(48 + r4) * 64 + csw, dst_ + 3072); \
  } while (0)

  int sw0 = (c31 & 3) << 4;
  float res[4];
  STAGE(0, 0);
#pragma unroll
  for (int p = 0; p < 4; ++p) {
    if (p < 3) STAGE((p + 1) & 1, p + 1);
    if (p < 3) { asm volatile("s_waitcnt vmcnt(4)" ::: "memory"); }
    else       { asm volatile("s_waitcnt vmcnt(0)" ::: "memory"); }
    const char* tb = (const char*)&ebuf[w][p & 1][0];
    f4 e0a = *(const f4*)(tb + c31 * 64 + ((h * 32) ^ sw0));
    f4 e0b = *(const f4*)(tb + c31 * 64 + ((h * 32 + 16) ^ sw0));
    f4 e1a = *(const f4*)(tb + (32 + c31) * 64 + ((h * 32) ^ sw0));
    f4 e1b = *(const f4*)(tb + (32 + c31) * 64 + ((h * 32 + 16) ^ sw0));
    union { h8 v; h2 q[4]; } u0, u1;
    u0.q[0] = pkrtz(e0a[0], e0a[1]); u0.q[1] = pkrtz(e0a[2], e0a[3]);
    u0.q[2] = pkrtz(e0b[0], e0b[1]); u0.q[3] = pkrtz(e0b[2], e0b[3]);
    u1.q[0] = pkrtz(e1a[0], e1a[1]); u1.q[1] = pkrtz(e1a[2], e1a[3]);
    u1.q[2] = pkrtz(e1b[0], e1b[1]); u1.q[3] = pkrtz(e1b[2], e1b[3]);
    float a00 = 0.f, a01 = 0.f, a10 = 0.f, a11 = 0.f;
    {
      fv16 hA0 = __builtin_amdgcn_mfma_f32_32x32x16_f16(aw0, u0.v, z, 0, 0, 0);
      fv16 hA1 = __builtin_amdgcn_mfma_f32_32x32x16_f16(aw0, u1.v, z, 0, 0, 0);
#pragma unroll
      for (int r = 0; r < 16; ++r) {
        float bb = (float)pb[r][0];
        float ww = (float)pw[r][0];
        if (r & 1) {
          a01 = fmaf(ww, frcp(fexp2(hA0[r] + bb) + 1.f), a01);
          a11 = fmaf(ww, frcp(fexp2(hA1[r] + bb) + 1.f), a11);
        } else {
          a00 = fmaf(ww, frcp(fexp2(hA0[r] + bb) + 1.f), a00);
          a10 = fmaf(ww, frcp(fexp2(hA1[r] + bb) + 1.f), a10);
        }
      }
    }
    {
      fv16 hB0 = __builtin_amdgcn_mfma_f32_32x32x16_f16(aw1, u0.v, z, 0, 0, 0);
      fv16 hB1 = __builtin_amdgcn_mfma_f32_32x32x16_f16(aw1, u1.v, z, 0, 0, 0);
#pragma unroll
      for (int r = 0; r < 16; ++r) {
        float bb = (float)pb[r][1];
        float ww = (float)pw[r][1];
        if (r & 1) {
          a01 = fmaf(ww, frcp(fexp2(hB0[r] + bb) + 1.f), a01);
          a11 = fmaf(ww, frcp(fexp2(hB1[r] + bb) + 1.f), a11);
        } else {
          a00 = fmaf(ww, frcp(fexp2(hB0[r] + bb) + 1.f), a00);
          a10 = fmaf(ww, frcp(fexp2(hB1[r] + bb) + 1.f), a10);
        }
      }
    }
    float p0 = a00 + a01;
    float p1 = a10 + a11;
    p0 += __shfl_xor(p0, 32, 64);
    p1 += __shfl_xor(p1, 32, 64);
    res[p] = h ? p1 : p0;
  }
#undef STAGE
#pragma unroll
  for (int p = 0; p < 4; ++p) {
    int idx = kq0 + p * 64 + 32 * h + c31;
    orow[idx] = m4[p] ? (_Float16)(-30000.0f) : (_Float16)fmaf(-C2, res[p], base);
  }
}

// ---------- fused attention (unchanged from R11-R13 winner) ----------
__global__ __launch_bounds__(256) void k_attn(
    const _Float16* __restrict__ Qh, const _Float16* __restrict__ Kh,
    const _Float16* __restrict__ Vt, const _Float16* __restrict__ biasH,
    float* __restrict__ ctx, float* __restrict__ attn) {
  int bid = blockIdx.x;
  int b = bid & 7;           // XCD-pinned batch
  int t_ = bid >> 3;
  int hh = t_ & 7;
  int qb = t_ >> 3;
  int bh = b * 8 + hh;
  int tid = threadIdx.x;
  int w = tid >> 6, l = tid & 63;
  int g = l >> 4, s = l & 15;
  int q0 = qb * 64 + w * 16;

  const _Float16* Qw = Qh + ((long)bh * NN + q0) * DK;
  const char* Kbase = (const char*)(Kh + (long)bh * NN * DK);
  const char* Vbase = (const char*)(Vt + (long)bh * DK * NN);
  const char* Bbase = (const char*)(biasH + (long)b * NN * NN + (long)(qb * 64) * NN);
  h8 aQ0 = *reinterpret_cast<const h8*>(Qw + s * DK + 8 * g);
  h8 aQ1 = *reinterpret_cast<const h8*>(Qw + s * DK + 32 + 8 * g);
  const f4 z4 = {0.f, 0.f, 0.f, 0.f};

  __shared__ __align__(16) _Float16 kt[2][32 * 64];
  __shared__ __align__(16) _Float16 vt2[2][64 * 32];
  __shared__ __align__(16) _Float16 bt[2][64 * 32];
  __shared__ float pf[4][16][33];

  int krow = tid >> 3;
  int kcol = ((tid & 7) * 16) ^ ((krow & 7) << 4);
  int vrow = tid >> 2;
  int vcol = ((tid & 3) * 16) ^ ((vrow & 3) << 4);
  int brow = tid >> 2;
  int bcol = (tid & 3) * 16;
  int wofs = w << 10;

  int ksw = (s & 7) << 4;
  int vswz = (s & 3) << 4;

#define STK(buf, c0) gl16(Kbase + (long)((c0) + krow) * 128 + kcol, (char*)kt[buf] + wofs)
#define STV(buf, c0) gl16(Vbase + (long)vrow * 2048 + (c0) * 2 + vcol, (char*)vt2[buf] + wofs)
#define STB(buf, c0) gl16(Bbase + (long)brow * 2048 + (c0) * 2 + bcol, (char*)bt[buf] + wofs)
#define BIAS(buf, j, kvl) ((float)*(const _Float16*)((const char*)bt[buf] + (w * 16 + 4 * g + (j)) * 64 + (kvl) * 2))

  float ls0 = 0.f, ls1 = 0.f, ls2 = 0.f, ls3 = 0.f;
  STK(0, 0); STB(0, 0);
  {
    int buf = 0;
    for (int c0 = 0; c0 < NN; c0 += 32, buf ^= 1) {
      __syncthreads();
      if (c0 + 32 < NN) { STK(buf ^ 1, c0 + 32); STB(buf ^ 1, c0 + 32); }
      const char* kbuf = (const char*)kt[buf];
      h8 k0 = *(const h8*)(kbuf + s * 128 + ((16 * g) ^ ksw));
      h8 k1 = *(const h8*)(kbuf + s * 128 + ((64 + 16 * g) ^ ksw));
      f4 acc = __builtin_amdgcn_mfma_f32_16x16x32_f16(aQ0, k0, z4, 0, 0, 0);
      acc = __builtin_amdgcn_mfma_f32_16x16x32_f16(aQ1, k1, acc, 0, 0, 0);
      ls0 += fexp2(acc[0] + BIAS(buf, 0, s));
      ls1 += fexp2(acc[1] + BIAS(buf, 1, s));
      ls2 += fexp2(acc[2] + BIAS(buf, 2, s));
      ls3 += fexp2(acc[3] + BIAS(buf, 3, s));
      k0 = *(const h8*)(kbuf + (16 + s) * 128 + ((16 * g) ^ ksw));
      k1 = *(const h8*)(kbuf + (16 + s) * 128 + ((64 + 16 * g) ^ ksw));
      acc = __builtin_amdgcn_mfma_f32_16x16x32_f16(aQ0, k0, z4, 0, 0, 0);
      acc = __builtin_amdgcn_mfma_f32_16x16x32_f16(aQ1, k1, acc, 0, 0, 0);
      ls0 += fexp2(acc[0] + BIAS(buf, 0, 16 + s));
      ls1 += fexp2(acc[1] + BIAS(buf, 1, 16 + s));
      ls2 += fexp2(acc[2] + BIAS(buf, 2, 16 + s));
      ls3 += fexp2(acc[3] + BIAS(buf, 3, 16 + s));
    }
  }
#pragma unroll
  for (int m = 1; m < 16; m <<= 1) {
    ls0 += __shfl_xor(ls0, m, 64);
    ls1 += __shfl_xor(ls1, m, 64);
    ls2 += __shfl_xor(ls2, m, 64);
    ls3 += __shfl_xor(ls3, m, 64);
  }
  float iv0 = frcp(ls0), iv1 = frcp(ls1), iv2 = frcp(ls2), iv3 = frcp(ls3);

  f4 ca0 = {0.f,0.f,0.f,0.f}, ca1 = {0.f,0.f,0.f,0.f};
  f4 ca2 = {0.f,0.f,0.f,0.f}, ca3 = {0.f,0.f,0.f,0.f};
  float* attnw = attn + ((long)bh * NN + q0) * NN;
  int sr = l >> 3, sc = (l & 7) * 4;
  __syncthreads();
  STK(0, 0); STV(0, 0); STB(0, 0);
  {
    int buf = 0;
    for (int c0 = 0; c0 < NN; c0 += 32, buf ^= 1) {
      __syncthreads();
      if (c0 + 32 < NN) { STK(buf ^ 1, c0 + 32); STV(buf ^ 1, c0 + 32); STB(buf ^ 1, c0 + 32); }
      const char* kbuf = (const char*)kt[buf];
      const char* vbuf = (const char*)vt2[buf];
      h8 k0 = *(const h8*)(kbuf + s * 128 + ((16 * g) ^ ksw));
      h8 k1 = *(const h8*)(kbuf + s * 128 + ((64 + 16 * g) ^ ksw));
      f4 acc = __builtin_amdgcn_mfma_f32_16x16x32_f16(aQ0, k0, z4, 0, 0, 0);
      acc = __builtin_amdgcn_mfma_f32_16x16x32_f16(aQ1, k1, acc, 0, 0, 0);
      pf[w][4 * g + 0][s] = fexp2(acc[0] + BIAS(buf, 0, s)) * iv0;
      pf[w][4 * g + 1][s] = fexp2(acc[1] + BIAS(buf, 1, s)) * iv1;
      pf[w][4 * g + 2][s] = fexp2(acc[2] + BIAS(buf, 2, s)) * iv2;
      pf[w][4 * g + 3][s] = fexp2(acc[3] + BIAS(buf, 3, s)) * iv3;
      k0 = *(const h8*)(kbuf + (16 + s) * 128 + ((16 * g) ^ ksw));
      k1 = *(const h8*)(kbuf + (16 + s) * 128 + ((64 + 16 * g) ^ ksw));
      acc = __builtin_amdgcn_mfma_f32_16x16x32_f16(aQ0, k0, z4, 0, 0, 0);
      acc = __builtin_amdgcn_mfma_f32_16x16x32_f16(aQ1, k1, acc, 0, 0, 0);
      pf[w][4 * g + 0][16 + s] = fexp2(acc[0] + BIAS(buf, 0, 16 + s)) * iv0;
      pf[w][4 * g + 1][16 + s] = fexp2(acc[1] + BIAS(buf, 1, 16 + s)) * iv1;
      pf[w][4 * g + 2][16 + s] = fexp2(acc[2] + BIAS(buf, 2, 16 + s)) * iv2;
      pf[w][4 * g + 3][16 + s] = fexp2(acc[3] + BIAS(buf, 3, 16 + s)) * iv3;
      f4 row0 = *reinterpret_cast<const f4*>(&pf[w][sr][sc]);
      f4 row1 = *reinterpret_cast<const f4*>(&pf[w][sr + 8][sc]);
      *reinterpret_cast<f4*>(attnw + (long)sr * NN + c0 + sc) = row0;
      *reinterpret_cast<f4*>(attnw + (long)(sr + 8) * NN + c0 + sc) = row1;
      f4 pa = *reinterpret_cast<const f4*>(&pf[w][s][8 * g]);
      f4 pb4 = *reinterpret_cast<const f4*>(&pf[w][s][8 * g + 4]);
      union { h8 v; h2 q[4]; } up;
      up.q[0] = pkrtz(pa[0], pa[1]);  up.q[1] = pkrtz(pa[2], pa[3]);
      up.q[2] = pkrtz(pb4[0], pb4[1]); up.q[3] = pkrtz(pb4[2], pb4[3]);
      h8 aP = up.v;
      h8 bv0 = *(const h8*)(vbuf + (s)      * 64 + ((16 * g) ^ vswz));
      h8 bv1 = *(const h8*)(vbuf + (16 + s) * 64 + ((16 * g) ^ vswz));
      h8 bv2 = *(const h8*)(vbuf + (32 + s) * 64 + ((16 * g) ^ vswz));
      h8 bv3 = *(const h8*)(vbuf + (48 + s) * 64 + ((16 * g) ^ vswz));
      ca0 = __builtin_amdgcn_mfma_f32_16x16x32_f16(aP, bv0, ca0, 0, 0, 0);
      ca1 = __builtin_amdgcn_mfma_f32_16x16x32_f16(aP, bv1, ca1, 0, 0, 0);
      ca2 = __builtin_amdgcn_mfma_f32_16x16x32_f16(aP, bv2, ca2, 0, 0, 0);
      ca3 = __builtin_amdgcn_mfma_f32_16x16x32_f16(aP, bv3, ca3, 0, 0, 0);
    }
  }
  float* cw = ctx + ((long)bh * NN + q0) * DK;
#pragma unroll
  for (int j = 0; j < 4; ++j) {
    cw[(4 * g + j) * DK + 0  + s] = ca0[j];
    cw[(4 * g + j) * DK + 16 + s] = ca1[j];
    cw[(4 * g + j) * DK + 32 + s] = ca2[j];
    cw[(4 * g + j) * DK + 48 + s] = ca3[j];
  }
#undef STK
#undef STV
#undef STB
#undef BIAS
}

extern "C" void kernel_launch(void* const* d_in, const int* in_sizes, int n_in,
                              void* d_out, int out_size, void* d_ws, size_t ws_size,
                              hipStream_t stream) {
  const float* Q = (const float*)d_in[0];
  const float* K = (const float*)d_in[1];
  const float* V = (const float*)d_in[2];
  const void* mask = d_in[3];
  const float* edge = (const float*)d_in[4];
  const float* W1 = (const float*)d_in[5];
  const float* b1 = (const float*)d_in[6];
  const float* W2 = (const float*)d_in[7];
  const float* b2 = (const float*)d_in[8];
  float* ctx = (float*)d_out;
  float* attn = ctx + QSZ;                  // outputs: context then attn
  char* ws = (char*)d_ws;
  if (ws_size < WS_NEED) return;
  _Float16* Qh = (_Float16*)(ws + OFF_QH);
  _Float16* Kh = (_Float16*)(ws + OFF_KH);
  _Float16* Vt = (_Float16*)(ws + OFF_VT);
  _Float16* biasM = (_Float16*)(ws + OFF_BIAS);

  k_front<<<17408, 256, 0, stream>>>(Q, K, V, mask, edge, W1, b1, W2, b2,
                                     Qh, Kh, Vt, biasM);
  k_attn<<<1024, 256, 0, stream>>>(Qh, Kh, Vt, biasM, ctx, attn);
}

// Round 16
// 246.337 us; speedup vs baseline: 1.1349x; 1.0922x over previous
//
#include <hip/hip_runtime.h>
#include <stdint.h>

// Problem constants
constexpr int NB = 8, NH = 8, NN = 1024, DK = 64, ED = 16;
constexpr long QSZ = (long)NB * NH * NN * DK;       // 4,194,304

typedef _Float16 h8 __attribute__((ext_vector_type(8)));
typedef _Float16 h4 __attribute__((ext_vector_type(4)));
typedef _Float16 h2 __attribute__((ext_vector_type(2)));
typedef float f4 __attribute__((ext_vector_type(4)));
typedef float fv16 __attribute__((ext_vector_type(16)));

// ws layout (bytes)
constexpr size_t OFF_QH = 0;                         // 8 MiB fp16 (pre-scaled by 0.125*log2e)
constexpr size_t OFF_KH = 8388608;                   // 8 MiB fp16
constexpr size_t OFF_VT = 16777216;                  // 8 MiB fp16 (transposed [bh][d][k])
constexpr size_t OFF_BIAS = 25165824;                // 16 MiB fp16 (bias*log2e, masked=-30000)
constexpr size_t WS_NEED = OFF_BIAS + 16777216;

constexpr float LG2E = 1.4426950408889634f;          // log2(e)
constexpr float C2 = 2.8853900817779268f;            // 2*log2(e)
constexpr float QS = 0.125f * LG2E;                  // fold 1/sqrt(dk) and log2e into Q

static __device__ __forceinline__ float fexp2(float x) {
  float r; asm("v_exp_f32 %0, %1" : "=v"(r) : "v"(x)); return r;
}
static __device__ __forceinline__ float frcp(float x) {
  float r; asm("v_rcp_f32 %0, %1" : "=v"(r) : "v"(x)); return r;
}
static __device__ __forceinline__ h2 pkrtz(float a, float b) {
  return __builtin_bit_cast(h2, __builtin_amdgcn_cvt_pkrtz(a, b));
}
// async global->LDS, 16B per lane; lptr must be WAVE-UNIFORM (HW scatters lane i to lptr + i*16)
static __device__ __forceinline__ void gl16(const void* g, void* l) {
  __builtin_amdgcn_global_load_lds(
      (const __attribute__((address_space(1))) uint32_t*)g,
      (__attribute__((address_space(3))) uint32_t*)l, 16, 0, 0);
}

// ---------- merged front kernel: bias MLP (blocks 0..8191) + Q/K/V prep (8192..17407) ----------
// Bias blocks self-detect mask width (scan first 4KB: int32 0/1 never has nonzero
// bytes at %4!=0). Mask-aware edge staging: masked rows (~50%) redirect their
// global_load_lds SOURCE to the tile's row 0, so fully-masked 128B line-pairs are
// never fetched from HBM (expected ~25% edge-fetch cut). Garbage staged for masked
// columns is confined to masked lanes (shfl(32) partner = same column) and the
// output is m4-selected to -30000 regardless.
__global__ __launch_bounds__(256, 3) void k_front(
    const float* __restrict__ Q, const float* __restrict__ K, const float* __restrict__ V,
    const void* __restrict__ maskp, const float* __restrict__ edge,
    const float* __restrict__ W1, const float* __restrict__ b1,
    const float* __restrict__ W2, const float* __restrict__ b2,
    _Float16* __restrict__ Qh, _Float16* __restrict__ Kh, _Float16* __restrict__ Vt,
    _Float16* __restrict__ biasM) {
  int bid = blockIdx.x;
  int tid = threadIdx.x;
  if (bid >= 8192) {
    // ---------------- prep path ----------------
    int pb_ = bid - 8192;
    if (pb_ < 8192) {
      int i = pb_ * 256 + tid;
      const int n4 = (int)(QSZ / 4);
      if (i < n4) {
        float4 v = reinterpret_cast<const float4*>(Q)[i];
        h4 o; o[0] = (_Float16)(v.x * QS); o[1] = (_Float16)(v.y * QS);
              o[2] = (_Float16)(v.z * QS); o[3] = (_Float16)(v.w * QS);
        reinterpret_cast<h4*>(Qh)[i] = o;
      } else {
        int j = i - n4;
        float4 v = reinterpret_cast<const float4*>(K)[j];
        h4 o; o[0] = (_Float16)v.x; o[1] = (_Float16)v.y;
              o[2] = (_Float16)v.z; o[3] = (_Float16)v.w;
        reinterpret_cast<h4*>(Kh)[j] = o;
      }
    } else {
      int wid = ((pb_ - 8192) * 256 + tid) >> 6;
      int lane = tid & 63;
      int bh = wid >> 6;
      int k0 = (wid & 63) << 4;
      const float* Vb = V + (long)bh * NN * DK;
      _Float16* Vo = Vt + (long)bh * DK * NN + (long)lane * NN + k0;
      h8 p0, p1;
#pragma unroll
      for (int i = 0; i < 16; ++i) {
        float v = Vb[(long)(k0 + i) * DK + lane];
        if (i < 8) p0[i] = (_Float16)v; else p1[i - 8] = (_Float16)v;
      }
      *reinterpret_cast<h8*>(Vo) = p0;
      *reinterpret_cast<h8*>(Vo + 8) = p1;
    }
    return;
  }
  // ---------------- bias path ----------------
  int bq = bid;
  int w = tid >> 6, l = tid & 63;
  int h = l >> 5, c31 = l & 31;

  // self-detect mask element width: scan first 4096 bytes (coalesced, L2-hot)
  __shared__ int sh4[4];
  {
    int4 mv = reinterpret_cast<const int4*>(maskp)[tid];
    int any = (mv.x | mv.y | mv.z | mv.w) & 0xFFFFFF00;
    unsigned long long bal = __ballot(any != 0);
    if ((tid & 63) == 0) sh4[tid >> 6] = (bal != 0) ? 1 : 0;
  }
  __syncthreads();
  bool isbool = (sh4[0] | sh4[1] | sh4[2] | sh4[3]) != 0;

  h8 aw0, aw1;
#pragma unroll
  for (int j = 0; j < 8; ++j) {
    aw0[j] = (_Float16)(W1[(8 * h + j) * 64 + 0  + c31] * C2);
    aw1[j] = (_Float16)(W1[(8 * h + j) * 64 + 32 + c31] * C2);
  }
  h2 pb[16], pw[16];
  float sw = 0.f;
#pragma unroll
  for (int r = 0; r < 16; ++r) {
    int dr = (r & 3) + 8 * (r >> 2) + 4 * h;
    float b0 = b1[dr] * C2, b1v = b1[32 + dr] * C2;
    float w0 = W2[dr], w1v = W2[32 + dr];
    pb[r] = pkrtz(b0, b1v);
    pw[r] = pkrtz(w0, w1v);
    sw += w0 + w1v;
  }
  sw += __shfl_xor(sw, 32, 64);
  float base = (sw + b2[0]) * LG2E;

  const char* erow_b = (const char*)(edge + (long)bq * NN * ED);  // 64B per kv row
  _Float16* orow = biasM + (long)bq * NN;
  const int* mrowi = (const int*)maskp + (long)bq * NN;
  const unsigned char* mrowb = (const unsigned char*)maskp + (long)bq * NN;

  fv16 z;
#pragma unroll
  for (int r = 0; r < 16; ++r) z[r] = 0.f;

  int kq0 = w * 256;
  // output-column masks
  int m4[4];
#pragma unroll
  for (int p = 0; p < 4; ++p) {
    int idx = kq0 + p * 64 + 32 * h + c31;
    m4[p] = isbool ? (int)mrowb[idx] : mrowi[idx];
  }

  __shared__ __align__(16) float ebuf[4][2][1024];
  int r4 = l >> 2;
  int csw = ((l & 3) * 16) ^ ((r4 & 3) << 4);
  // staged-row masks: bit (p*4+j) = mask of row kq0 + p*64 + j*16 + r4
  unsigned mbits = 0;
#pragma unroll
  for (int p = 0; p < 4; ++p)
#pragma unroll
    for (int j = 0; j < 4; ++j) {
      int row = kq0 + p * 64 + j * 16 + r4;
      int mv = isbool ? (int)mrowb[row] : mrowi[row];
      mbits |= (mv ? 1u : 0u) << (p * 4 + j);
    }
#define STAGE(buf, p) do { \
    const char* s0_ = erow_b + (long)(kq0 + (p) * 64) * 64; \
    unsigned mb_ = mbits >> ((p) * 4); \
    char* dst_ = (char*)&ebuf[w][buf][0]; \
    gl16((mb_ & 1) ? s0_ + csw : s0_ + (long)(r4) * 64 + csw, dst_); \
    gl16((mb_ & 2) ? s0_ + csw : s0_ + (long)(16 + r4) * 64 + csw, dst_ + 1024); \
    gl16((mb_ & 4) ? s0_ + csw : s0_ + (long)(32 + r4) * 64 + csw, dst_ + 2048); \
    gl16((mb_ & 8) ? s0_ + csw : s0_ + (long)(48 + r4) * 64 + csw, dst_ + 3072); \
  } while (0)

  int sw0 = (c31 & 3) << 4;
  float res[4];
  STAGE(0, 0);
#pragma unroll
  for (int p = 0; p < 4; ++p) {
    if (p < 3) STAGE((p + 1) & 1, p + 1);
    if (p < 3) { asm volatile("s_waitcnt vmcnt(4)" ::: "memory"); }
    else       { asm volatile("s_waitcnt vmcnt(0)" ::: "memory"); }
    const char* tb = (const char*)&ebuf[w][p & 1][0];
    f4 e0a = *(const f4*)(tb + c31 * 64 + ((h * 32) ^ sw0));
    f4 e0b = *(const f4*)(tb + c31 * 64 + ((h * 32 + 16) ^ sw0));
    f4 e1a = *(const f4*)(tb + (32 + c31) * 64 + ((h * 32) ^ sw0));
    f4 e1b = *(const f4*)(tb + (32 + c31) * 64 + ((h * 32 + 16) ^ sw0));
    union { h8 v; h2 q[4]; } u0, u1;
    u0.q[0] = pkrtz(e0a[0], e0a[1]); u0.q[1] = pkrtz(e0a[2], e0a[3]);
    u0.q[2] = pkrtz(e0b[0], e0b[1]); u0.q[3] = pkrtz(e0b[2], e0b[3]);
    u1.q[0] = pkrtz(e1a[0], e1a[1]); u1.q[1] = pkrtz(e1a[2], e1a[3]);
    u1.q[2] = pkrtz(e1b[0], e1b[1]); u1.q[3] = pkrtz(e1b[2], e1b[3]);
    float a00 = 0.f, a01 = 0.f, a10 = 0.f, a11 = 0.f;
    {
      fv16 hA0 = __builtin_amdgcn_mfma_f32_32x32x16_f16(aw0, u0.v, z, 0, 0, 0);
      fv16 hA1 = __builtin_amdgcn_mfma_f32_32x32x16_f16(aw0, u1.v, z, 0, 0, 0);
#pragma unroll
      for (int r = 0; r < 16; ++r) {
        float bb = (float)pb[r][0];
        float ww = (float)pw[r][0];
        if (r & 1) {
          a01 = fmaf(ww, frcp(fexp2(hA0[r] + bb) + 1.f), a01);
          a11 = fmaf(ww, frcp(fexp2(hA1[r] + bb) + 1.f), a11);
        } else {
          a00 = fmaf(ww, frcp(fexp2(hA0[r] + bb) + 1.f), a00);
          a10 = fmaf(ww, frcp(fexp2(hA1[r] + bb) + 1.f), a10);
        }
      }
    }
    {
      fv16 hB0 = __builtin_amdgcn_mfma_f32_32x32x16_f16(aw1, u0.v, z, 0, 0, 0);
      fv16 hB1 = __builtin_amdgcn_mfma_f32_32x32x16_f16(aw1, u1.v, z, 0, 0, 0);
#pragma unroll
      for (int r = 0; r < 16; ++r) {
        float bb = (float)pb[r][1];
        float ww = (float)pw[r][1];
        if (r & 1) {
          a01 = fmaf(ww, frcp(fexp2(hB0[r] + bb) + 1.f), a01);
          a11 = fmaf(ww, frcp(fexp2(hB1[r] + bb) + 1.f), a11);
        } else {
          a00 = fmaf(ww, frcp(fexp2(hB0[r] + bb) + 1.f), a00);
          a10 = fmaf(ww, frcp(fexp2(hB1[r] + bb) + 1.f), a10);
        }
      }
    }
    float p0 = a00 + a01;
    float p1 = a10 + a11;
    p0 += __shfl_xor(p0, 32, 64);
    p1 += __shfl_xor(p1, 32, 64);
    res[p] = h ? p1 : p0;
  }
#undef STAGE
#pragma unroll
  for (int p = 0; p < 4; ++p) {
    int idx = kq0 + p * 64 + 32 * h + c31;
    orow[idx] = m4[p] ? (_Float16)(-30000.0f) : (_Float16)fmaf(-C2, res[p], base);
  }
}

// ---------- fused attention (unchanged from R11-R13 winner) ----------
__global__ __launch_bounds__(256) void k_attn(
    const _Float16* __restrict__ Qh, const _Float16* __restrict__ Kh,
    const _Float16* __restrict__ Vt, const _Float16* __restrict__ biasH,
    float* __restrict__ ctx, float* __restrict__ attn) {
  int bid = blockIdx.x;
  int b = bid & 7;           // XCD-pinned batch
  int t_ = bid >> 3;
  int hh = t_ & 7;
  int qb = t_ >> 3;
  int bh = b * 8 + hh;
  int tid = threadIdx.x;
  int w = tid >> 6, l = tid & 63;
  int g = l >> 4, s = l & 15;
  int q0 = qb * 64 + w * 16;

  const _Float16* Qw = Qh + ((long)bh * NN + q0) * DK;
  const char* Kbase = (const char*)(Kh + (long)bh * NN * DK);
  const char* Vbase = (const char*)(Vt + (long)bh * DK * NN);
  const char* Bbase = (const char*)(biasH + (long)b * NN * NN + (long)(qb * 64) * NN);
  h8 aQ0 = *reinterpret_cast<const h8*>(Qw + s * DK + 8 * g);
  h8 aQ1 = *reinterpret_cast<const h8*>(Qw + s * DK + 32 + 8 * g);
  const f4 z4 = {0.f, 0.f, 0.f, 0.f};

  __shared__ __align__(16) _Float16 kt[2][32 * 64];
  __shared__ __align__(16) _Float16 vt2[2][64 * 32];
  __shared__ __align__(16) _Float16 bt[2][64 * 32];
  __shared__ float pf[4][16][33];

  int krow = tid >> 3;
  int kcol = ((tid & 7) * 16) ^ ((krow & 7) << 4);
  int vrow = tid >> 2;
  int vcol = ((tid & 3) * 16) ^ ((vrow & 3) << 4);
  int brow = tid >> 2;
  int bcol = (tid & 3) * 16;
  int wofs = w << 10;

  int ksw = (s & 7) << 4;
  int vswz = (s & 3) << 4;

#define STK(buf, c0) gl16(Kbase + (long)((c0) + krow) * 128 + kcol, (char*)kt[buf] + wofs)
#define STV(buf, c0) gl16(Vbase + (long)vrow * 2048 + (c0) * 2 + vcol, (char*)vt2[buf] + wofs)
#define STB(buf, c0) gl16(Bbase + (long)brow * 2048 + (c0) * 2 + bcol, (char*)bt[buf] + wofs)
#define BIAS(buf, j, kvl) ((float)*(const _Float16*)((const char*)bt[buf] + (w * 16 + 4 * g + (j)) * 64 + (kvl) * 2))

  float ls0 = 0.f, ls1 = 0.f, ls2 = 0.f, ls3 = 0.f;
  STK(0, 0); STB(0, 0);
  {
    int buf = 0;
    for (int c0 = 0; c0 < NN; c0 += 32, buf ^= 1) {
      __syncthreads();
      if (c0 + 32 < NN) { STK(buf ^ 1, c0 + 32); STB(buf ^ 1, c0 + 32); }
      const char* kbuf = (const char*)kt[buf];
      h8 k0 = *(const h8*)(kbuf + s * 128 + ((16 * g) ^ ksw));
      h8 k1 = *(const h8*)(kbuf + s * 128 + ((64 + 16 * g) ^ ksw));
      f4 acc = __builtin_amdgcn_mfma_f32_16x16x32_f16(aQ0, k0, z4, 0, 0, 0);
      acc = __builtin_amdgcn_mfma_f32_16x16x32_f16(aQ1, k1, acc, 0, 0, 0);
      ls0 += fexp2(acc[0] + BIAS(buf, 0, s));
      ls1 += fexp2(acc[1] + BIAS(buf, 1, s));
      ls2 += fexp2(acc[2] + BIAS(buf, 2, s));
      ls3 += fexp2(acc[3] + BIAS(buf, 3, s));
      k0 = *(const h8*)(kbuf + (16 + s) * 128 + ((16 * g) ^ ksw));
      k1 = *(const h8*)(kbuf + (16 + s) * 128 + ((64 + 16 * g) ^ ksw));
      acc = __builtin_amdgcn_mfma_f32_16x16x32_f16(aQ0, k0, z4, 0, 0, 0);
      acc = __builtin_amdgcn_mfma_f32_16x16x32_f16(aQ1, k1, acc, 0, 0, 0);
      ls0 += fexp2(acc[0] + BIAS(buf, 0, 16 + s));
      ls1 += fexp2(acc[1] + BIAS(buf, 1, 16 + s));
      ls2 += fexp2(acc[2] + BIAS(buf, 2, 16 + s));
      ls3 += fexp2(acc[3] + BIAS(buf, 3, 16 + s));
    }
  }
#pragma unroll
  for (int m = 1; m < 16; m <<= 1) {
    ls0 += __shfl_xor(ls0, m, 64);
    ls1 += __shfl_xor(ls1, m, 64);
    ls2 += __shfl_xor(ls2, m, 64);
    ls3 += __shfl_xor(ls3, m, 64);
  }
  float iv0 = frcp(ls0), iv1 = frcp(ls1), iv2 = frcp(ls2), iv3 = frcp(ls3);

  f4 ca0 = {0.f,0.f,0.f,0.f}, ca1 = {0.f,0.f,0.f,0.f};
  f4 ca2 = {0.f,0.f,0.f,0.f}, ca3 = {0.f,0.f,0.f,0.f};
  float* attnw = attn + ((long)bh * NN + q0) * NN;
  int sr = l >> 3, sc = (l & 7) * 4;
  __syncthreads();
  STK(0, 0); STV(0, 0); STB(0, 0);
  {
    int buf = 0;
    for (int c0 = 0; c0 < NN; c0 += 32, buf ^= 1) {
      __syncthreads();
      if (c0 + 32 < NN) { STK(buf ^ 1, c0 + 32); STV(buf ^ 1, c0 + 32); STB(buf ^ 1, c0 + 32); }
      const char* kbuf = (const char*)kt[buf];
      const char* vbuf = (const char*)vt2[buf];
      h8 k0 = *(const h8*)(kbuf + s * 128 + ((16 * g) ^ ksw));
      h8 k1 = *(const h8*)(kbuf + s * 128 + ((64 + 16 * g) ^ ksw));
      f4 acc = __builtin_amdgcn_mfma_f32_16x16x32_f16(aQ0, k0, z4, 0, 0, 0);
      acc = __builtin_amdgcn_mfma_f32_16x16x32_f16(aQ1, k1, acc, 0, 0, 0);
      pf[w][4 * g + 0][s] = fexp2(acc[0] + BIAS(buf, 0, s)) * iv0;
      pf[w][4 * g + 1][s] = fexp2(acc[1] + BIAS(buf, 1, s)) * iv1;
      pf[w][4 * g + 2][s] = fexp2(acc[2] + BIAS(buf, 2, s)) * iv2;
      pf[w][4 * g + 3][s] = fexp2(acc[3] + BIAS(buf, 3, s)) * iv3;
      k0 = *(const h8*)(kbuf + (16 + s) * 128 + ((16 * g) ^ ksw));
      k1 = *(const h8*)(kbuf + (16 + s) * 128 + ((64 + 16 * g) ^ ksw));
      acc = __builtin_amdgcn_mfma_f32_16x16x32_f16(aQ0, k0, z4, 0, 0, 0);
      acc = __builtin_amdgcn_mfma_f32_16x16x32_f16(aQ1, k1, acc, 0, 0, 0);
      pf[w][4 * g + 0][16 + s] = fexp2(acc[0] + BIAS(buf, 0, 16 + s)) * iv0;
      pf[w][4 * g + 1][16 + s] = fexp2(acc[1] + BIAS(buf, 1, 16 + s)) * iv1;
      pf[w][4 * g + 2][16 + s] = fexp2(acc[2] + BIAS(buf, 2, 16 + s)) * iv2;
      pf[w][4 * g + 3][16 + s] = fexp2(acc[3] + BIAS(buf, 3, 16 + s)) * iv3;
      f4 row0 = *reinterpret_cast<const f4*>(&pf[w][sr][sc]);
      f4 row1 = *reinterpret_cast<const f4*>(&pf[w][sr + 8][sc]);
      *reinterpret_cast<f4*>(attnw + (long)sr * NN + c0 + sc) = row0;
      *reinterpret_cast<f4*>(attnw + (long)(sr + 8) * NN + c0 + sc) = row1;
      f4 pa = *reinterpret_cast<const f4*>(&pf[w][s][8 * g]);
      f4 pb4 = *reinterpret_cast<const f4*>(&pf[w][s][8 * g + 4]);
      union { h8 v; h2 q[4]; } up;
      up.q[0] = pkrtz(pa[0], pa[1]);  up.q[1] = pkrtz(pa[2], pa[3]);
      up.q[2] = pkrtz(pb4[0], pb4[1]); up.q[3] = pkrtz(pb4[2], pb4[3]);
      h8 aP = up.v;
      h8 bv0 = *(const h8*)(vbuf + (s)      * 64 + ((16 * g) ^ vswz));
      h8 bv1 = *(const h8*)(vbuf + (16 + s) * 64 + ((16 * g) ^ vswz));
      h8 bv2 = *(const h8*)(vbuf + (32 + s) * 64 + ((16 * g) ^ vswz));
      h8 bv3 = *(const h8*)(vbuf + (48 + s) * 64 + ((16 * g) ^ vswz));
      ca0 = __builtin_amdgcn_mfma_f32_16x16x32_f16(aP, bv0, ca0, 0, 0, 0);
      ca1 = __builtin_amdgcn_mfma_f32_16x16x32_f16(aP, bv1, ca1, 0, 0, 0);
      ca2 = __builtin_amdgcn_mfma_f32_16x16x32_f16(aP, bv2, ca2, 0, 0, 0);
      ca3 = __builtin_amdgcn_mfma_f32_16x16x32_f16(aP, bv3, ca3, 0, 0, 0);
    }
  }
  float* cw = ctx + ((long)bh * NN + q0) * DK;
#pragma unroll
  for (int j = 0; j < 4; ++j) {
    cw[(4 * g + j) * DK + 0  + s] = ca0[j];
    cw[(4 * g + j) * DK + 16 + s] = ca1[j];
    cw[(4 * g + j) * DK + 32 + s] = ca2[j];
    cw[(4 * g + j) * DK + 48 + s] = ca3[j];
  }
#undef STK
#undef STV
#undef STB
#undef BIAS
}

extern "C" void kernel_launch(void* const* d_in, const int* in_sizes, int n_in,
                              void* d_out, int out_size, void* d_ws, size_t ws_size,
                              hipStream_t stream) {
  const float* Q = (const float*)d_in[0];
  const float* K = (const float*)d_in[1];
  const float* V = (const float*)d_in[2];
  const void* mask = d_in[3];
  const float* edge = (const float*)d_in[4];
  const float* W1 = (const float*)d_in[5];
  const float* b1 = (const float*)d_in[6];
  const float* W2 = (const float*)d_in[7];
  const float* b2 = (const float*)d_in[8];
  float* ctx = (float*)d_out;
  float* attn = ctx + QSZ;                  // outputs: context then attn
  char* ws = (char*)d_ws;
  if (ws_size < WS_NEED) return;
  _Float16* Qh = (_Float16*)(ws + OFF_QH);
  _Float16* Kh = (_Float16*)(ws + OFF_KH);
  _Float16* Vt = (_Float16*)(ws + OFF_VT);
  _Float16* biasM = (_Float16*)(ws + OFF_BIAS);

  k_front<<<17408, 256, 0, stream>>>(Q, K, V, mask, edge, W1, b1, W2, b2,
                                     Qh, Kh, Vt, biasM);
  k_attn<<<1024, 256, 0, stream>>>(Qh, Kh, Vt, biasM, ctx, attn);
}